// Round 1
// baseline (215.046 us; speedup 1.0000x reference)
//
#include <hip/hip_runtime.h>
#include <cstdint>
#include <cmath>

#define EPSV 1e-6f

typedef __attribute__((ext_vector_type(8))) short bf16x8;
typedef __attribute__((ext_vector_type(4))) float f32x4;

__device__ __forceinline__ short f2b(float f) {
  unsigned u = __float_as_uint(f);
  u = (u + 0x7fffu + ((u >> 16) & 1u)) >> 16;   // RNE fp32 -> bf16
  return (short)u;
}

// out[64,N] = X[64,K] @ W[N,K]^T  (bf16 MFMA, fp32 in/out)
template<int BN, int BK>
__global__ __launch_bounds__(256) void gemm_xwt(
    const float* __restrict__ X, const float* __restrict__ W,
    float* __restrict__ Out, int N, int K) {
  constexpr int NT = BN / 16;       // N-tiles per wave
  constexpr int KC = BK / 32;       // mfma K-steps per LDS tile
  constexpr int CH = BK / 8;        // 16B bf16 chunks per row
  __shared__ short As[64][BK];
  __shared__ short Ws[BN][BK];
  const int tid = threadIdx.x;
  const int lane = tid & 63;
  const int wv = tid >> 6;          // wave id = M-tile
  const int lrow = lane & 15;
  const int lk = lane >> 4;         // 0..3
  const int n0 = blockIdx.x * BN;

  f32x4 acc[NT];
#pragma unroll
  for (int i = 0; i < NT; ++i) acc[i] = (f32x4){0.f, 0.f, 0.f, 0.f};

  for (int k0 = 0; k0 < K; k0 += BK) {
    __syncthreads();
    // stage A tile: 64 x BK, fp32->bf16, chunk XOR-swizzle vs row
    for (int cid = tid; cid < 64 * CH; cid += 256) {
      const int r = cid / CH, c = cid % CH;
      const float* s = X + (size_t)r * K + k0 + c * 8;
      float4 f0 = *(const float4*)s;
      float4 f1 = *(const float4*)(s + 4);
      bf16x8 v;
      v[0]=f2b(f0.x); v[1]=f2b(f0.y); v[2]=f2b(f0.z); v[3]=f2b(f0.w);
      v[4]=f2b(f1.x); v[5]=f2b(f1.y); v[6]=f2b(f1.z); v[7]=f2b(f1.w);
      *(bf16x8*)&As[r][(c ^ (r & 7)) * 8] = v;
    }
    // stage W tile: BN x BK
    for (int cid = tid; cid < BN * CH; cid += 256) {
      const int r = cid / CH, c = cid % CH;
      const float* s = W + (size_t)(n0 + r) * K + k0 + c * 8;
      float4 f0 = *(const float4*)s;
      float4 f1 = *(const float4*)(s + 4);
      bf16x8 v;
      v[0]=f2b(f0.x); v[1]=f2b(f0.y); v[2]=f2b(f0.z); v[3]=f2b(f0.w);
      v[4]=f2b(f1.x); v[5]=f2b(f1.y); v[6]=f2b(f1.z); v[7]=f2b(f1.w);
      *(bf16x8*)&Ws[r][(c ^ (r & 7)) * 8] = v;
    }
    __syncthreads();
#pragma unroll
    for (int kc = 0; kc < KC; ++kc) {
      const int arow = wv * 16 + lrow;
      bf16x8 a = *(const bf16x8*)&As[arow][(((kc << 2) | lk) ^ (arow & 7)) * 8];
#pragma unroll
      for (int nt = 0; nt < NT; ++nt) {
        const int brow = nt * 16 + lrow;
        bf16x8 bb = *(const bf16x8*)&Ws[brow][(((kc << 2) | lk) ^ (brow & 7)) * 8];
        acc[nt] = __builtin_amdgcn_mfma_f32_16x16x32_bf16(a, bb, acc[nt], 0, 0, 0);
      }
    }
  }
  // C/D layout: col = lane&15, row = (lane>>4)*4 + i  [m89-verified]
#pragma unroll
  for (int nt = 0; nt < NT; ++nt)
#pragma unroll
    for (int i = 0; i < 4; ++i) {
      const int m = wv * 16 + lk * 4 + i;
      Out[(size_t)m * N + n0 + nt * 16 + lrow] = acc[nt][i];
    }
}

__device__ __forceinline__ float block_reduce_sum256(float v, float* red, int t) {
#pragma unroll
  for (int o = 32; o > 0; o >>= 1) v += __shfl_xor(v, o, 64);
  __syncthreads();                  // protect red[] reuse across calls
  if ((t & 63) == 0) red[t >> 6] = v;
  __syncthreads();
  return red[0] + red[1] + red[2] + red[3];
}

// one block per (b, head); 256 threads
__global__ __launch_bounds__(256) void state_update(
    const float* __restrict__ proj, const float* __restrict__ h,
    const float* __restrict__ B_prev, const float* __restrict__ x_prev,
    const float* __restrict__ theta_cumsum, const float* __restrict__ A_log,
    const float* __restrict__ B_bias, const float* __restrict__ C_bias,
    float* __restrict__ o_h, float* __restrict__ o_B,
    float* __restrict__ o_xp, float* __restrict__ o_th,
    float* __restrict__ ys) {
  const int bid = blockIdx.x;            // b*32 + hd
  const int b = bid >> 5, hd = bid & 31;
  const int t = threadIdx.x;
  const size_t pb = (size_t)b * 18496;

  __shared__ float sB[128], sC[128], sBp[128], sXp[128], sXv[128];
  __shared__ float red[8];
  __shared__ float yred[8][128];

  float aval = (t < 128) ? expf(A_log[hd * 128 + t]) : 0.f;
  float brv  = (t < 128) ? proj[pb + 8192 + hd * 128 + t] : 0.f;
  float crv  = (t < 128) ? proj[pb + 12288 + hd * 128 + t] : 0.f;
  if (t < 128) {
    sBp[t] = B_prev[(size_t)bid * 128 + t];
    float xp = proj[pb + hd * 128 + t];
    sXp[t] = xp;
    o_xp[(size_t)bid * 128 + t] = xp;
    sXv[t] = x_prev[(size_t)bid * 128 + t];
  }
  float sumA  = block_reduce_sum256(aval, red, t);
  float sumB2 = block_reduce_sum256(brv * brv, red, t);
  float sumC2 = block_reduce_sum256(crv * crv, red, t);

  const float dt_raw  = proj[pb + 16384 + hd];
  const float lam_raw = proj[pb + 16416 + hd];
  const float dt  = (dt_raw > 20.f) ? dt_raw : log1pf(expf(dt_raw));
  const float lam = 1.f / (1.f + expf(-lam_raw));
  const float A     = -sumA * (1.f / 128.f);
  const float alpha = expf(dt * A);
  const float beta  = (1.f - lam) * dt * alpha;
  const float gamma = lam * dt;
  const float rb = rsqrtf(sumB2 * (1.f / 128.f) + EPSV);
  const float rc = rsqrtf(sumC2 * (1.f / 128.f) + EPSV);

  if (t < 64) {
    float b0 = proj[pb + 8192 + hd * 128 + 2 * t];
    float b1 = proj[pb + 8192 + hd * 128 + 2 * t + 1];
    float c0 = proj[pb + 12288 + hd * 128 + 2 * t];
    float c1 = proj[pb + 12288 + hd * 128 + 2 * t + 1];
    b0 = b0 * rb + B_bias[hd * 128 + 2 * t];
    b1 = b1 * rb + B_bias[hd * 128 + 2 * t + 1];
    c0 = c0 * rc + C_bias[hd * 128 + 2 * t];
    c1 = c1 * rc + C_bias[hd * 128 + 2 * t + 1];
    const float th = theta_cumsum[(size_t)bid * 64 + t]
                   + proj[pb + 16448 + hd * 64 + t] * dt;
    o_th[(size_t)bid * 64 + t] = th;
    const float cth = cosf(th), sth = sinf(th);
    const float nb0 = b0 * cth - b1 * sth, nb1 = b0 * sth + b1 * cth;
    const float nc0 = c0 * cth - c1 * sth, nc1 = c0 * sth + c1 * cth;
    sB[2 * t] = nb0; sB[2 * t + 1] = nb1;
    sC[2 * t] = nc0; sC[2 * t + 1] = nc1;
    o_B[(size_t)bid * 128 + 2 * t] = nb0;
    o_B[(size_t)bid * 128 + 2 * t + 1] = nb1;
  }
  __syncthreads();

  // h_new = alpha*h + beta*Bp(x)xv + gamma*B(x)xp ; y[p] += C[n]*h_new[n][p]
  const int p4 = t & 31, nb = t >> 5;
  const float4 xp4 = *(const float4*)&sXp[p4 * 4];
  const float4 xv4 = *(const float4*)&sXv[p4 * 4];
  const size_t hbase = (size_t)bid * 16384;
  float4 ya = {0.f, 0.f, 0.f, 0.f};
  for (int n = nb; n < 128; n += 8) {
    const float4 hv = *(const float4*)&h[hbase + n * 128 + p4 * 4];
    const float cb = gamma * sB[n];
    const float cp = beta * sBp[n];
    float4 hn;
    hn.x = alpha * hv.x + cp * xv4.x + cb * xp4.x;
    hn.y = alpha * hv.y + cp * xv4.y + cb * xp4.y;
    hn.z = alpha * hv.z + cp * xv4.z + cb * xp4.z;
    hn.w = alpha * hv.w + cp * xv4.w + cb * xp4.w;
    *(float4*)&o_h[hbase + n * 128 + p4 * 4] = hn;
    const float cn = sC[n];
    ya.x += cn * hn.x; ya.y += cn * hn.y; ya.z += cn * hn.z; ya.w += cn * hn.w;
  }
  *(float4*)&yred[nb][p4 * 4] = ya;
  __syncthreads();
  if (t < 128) {
    float y = 0.f;
#pragma unroll
    for (int j = 0; j < 8; ++j) y += yred[j][t];
    const float zv = proj[pb + 4096 + hd * 128 + t];
    const float sig = 1.f / (1.f + expf(-zv));
    ys[(size_t)b * 4096 + hd * 128 + t] = y * zv * sig;
  }
}

extern "C" void kernel_launch(void* const* d_in, const int* in_sizes, int n_in,
                              void* d_out, int out_size, void* d_ws, size_t ws_size,
                              hipStream_t stream) {
  const float* x            = (const float*)d_in[0];
  const float* h            = (const float*)d_in[1];
  const float* B_prev       = (const float*)d_in[2];
  const float* x_prev       = (const float*)d_in[3];
  const float* theta_cumsum = (const float*)d_in[4];
  const float* W_in         = (const float*)d_in[5];
  const float* A_log        = (const float*)d_in[6];
  const float* B_bias       = (const float*)d_in[7];
  const float* C_bias       = (const float*)d_in[8];
  const float* W_out        = (const float*)d_in[9];

  float* out  = (float*)d_out;
  float* o_y  = out;                        // 64*2048
  float* o_h  = out + 131072;               // 64*32*128*128
  float* o_B  = o_h + 33554432;             // 64*32*128
  float* o_xp = o_B + 262144;               // 64*32*128
  float* o_th = o_xp + 262144;              // 64*32*64

  float* proj = (float*)d_ws;               // 64*18496 fp32
  float* ys   = proj + 1183744;             // 64*4096 fp32

  // 1) proj = x @ W_in^T   (N=18496, K=2048)
  gemm_xwt<32, 64><<<dim3(18496 / 32), dim3(256), 0, stream>>>(
      x, W_in, proj, 18496, 2048);
  // 2) per-(b,head) fused state update
  state_update<<<dim3(2048), dim3(256), 0, stream>>>(
      proj, h, B_prev, x_prev, theta_cumsum, A_log, B_bias, C_bias,
      o_h, o_B, o_xp, o_th, ys);
  // 3) y = ys @ W_out^T    (N=2048, K=4096)
  gemm_xwt<16, 64><<<dim3(2048 / 16), dim3(256), 0, stream>>>(
      ys, W_out, o_y, 2048, 4096);
}

// Round 2
// 164.849 us; speedup vs baseline: 1.3045x; 1.3045x over previous
//
#include <hip/hip_runtime.h>
#include <hip/hip_bf16.h>
#include <cstdint>
#include <cmath>

#define EPSV 1e-6f

typedef __attribute__((ext_vector_type(8))) short bf16x8;
typedef __attribute__((ext_vector_type(4))) float f32x4;

__device__ __forceinline__ short f2b(float f) {
  unsigned u = __float_as_uint(f);
  u = (u + 0x7fffu + ((u >> 16) & 1u)) >> 16;   // RNE fp32 -> bf16
  return (short)u;
}

__device__ __forceinline__ bf16x8 cvt8(float4 a, float4 b) {
  bf16x8 v;
  v[0]=f2b(a.x); v[1]=f2b(a.y); v[2]=f2b(a.z); v[3]=f2b(a.w);
  v[4]=f2b(b.x); v[5]=f2b(b.y); v[6]=f2b(b.z); v[7]=f2b(b.w);
  return v;
}

// fp32 -> bf16 bulk convert (for the tiny A matrix)
__global__ __launch_bounds__(256) void conv_bf16(
    const float* __restrict__ in, short* __restrict__ out, int n8) {
  const int i = blockIdx.x * 256 + threadIdx.x;
  if (i < n8) {
    float4 a = ((const float4*)in)[2 * i];
    float4 b = ((const float4*)in)[2 * i + 1];
    ((bf16x8*)out)[i] = cvt8(a, b);
  }
}

// Outp[ks][64][N] partial = Abf[64,K-slice] @ W[N,K-slice]^T
// One wave computes a full 64x16 strip for one K-slice. No LDS, no barriers:
// W streamed global->reg->bf16->MFMA (read exactly once); A bf16 from L2.
template<int KSLOG, int KSTEPS>
__global__ __launch_bounds__(256) void gemm_stream(
    const short* __restrict__ Abf, const float* __restrict__ W,
    float* __restrict__ Outp, int N, int K) {
  const int lane = threadIdx.x & 63;
  const int wid = blockIdx.x * 4 + (threadIdx.x >> 6);
  const int lrow = lane & 15, lk = lane >> 4;
  const int ks = wid & ((1 << KSLOG) - 1);
  const int n0 = (wid >> KSLOG) * 16;
  const int k0 = ks * (KSTEPS * 32);

  const float* wp = W + (size_t)(n0 + lrow) * K + k0 + lk * 8;
  const short* ap = Abf + (size_t)lrow * K + k0 + lk * 8;
  const size_t mstr = (size_t)16 * K;

  f32x4 acc0 = {0.f,0.f,0.f,0.f}, acc1 = {0.f,0.f,0.f,0.f};
  f32x4 acc2 = {0.f,0.f,0.f,0.f}, acc3 = {0.f,0.f,0.f,0.f};

  // prologue loads (k-step 0)
  float4 w0 = *(const float4*)wp;
  float4 w1 = *(const float4*)(wp + 4);
  bf16x8 a0 = *(const bf16x8*)(ap);
  bf16x8 a1 = *(const bf16x8*)(ap + mstr);
  bf16x8 a2 = *(const bf16x8*)(ap + 2 * mstr);
  bf16x8 a3 = *(const bf16x8*)(ap + 3 * mstr);

  for (int kk = 0; kk < KSTEPS - 1; ++kk) {
    wp += 32; ap += 32;
    // prefetch next k-step while current converts/MFMAs
    float4 nw0 = *(const float4*)wp;
    float4 nw1 = *(const float4*)(wp + 4);
    bf16x8 na0 = *(const bf16x8*)(ap);
    bf16x8 na1 = *(const bf16x8*)(ap + mstr);
    bf16x8 na2 = *(const bf16x8*)(ap + 2 * mstr);
    bf16x8 na3 = *(const bf16x8*)(ap + 3 * mstr);
    bf16x8 wb = cvt8(w0, w1);
    acc0 = __builtin_amdgcn_mfma_f32_16x16x32_bf16(a0, wb, acc0, 0, 0, 0);
    acc1 = __builtin_amdgcn_mfma_f32_16x16x32_bf16(a1, wb, acc1, 0, 0, 0);
    acc2 = __builtin_amdgcn_mfma_f32_16x16x32_bf16(a2, wb, acc2, 0, 0, 0);
    acc3 = __builtin_amdgcn_mfma_f32_16x16x32_bf16(a3, wb, acc3, 0, 0, 0);
    w0 = nw0; w1 = nw1; a0 = na0; a1 = na1; a2 = na2; a3 = na3;
  }
  {
    bf16x8 wb = cvt8(w0, w1);
    acc0 = __builtin_amdgcn_mfma_f32_16x16x32_bf16(a0, wb, acc0, 0, 0, 0);
    acc1 = __builtin_amdgcn_mfma_f32_16x16x32_bf16(a1, wb, acc1, 0, 0, 0);
    acc2 = __builtin_amdgcn_mfma_f32_16x16x32_bf16(a2, wb, acc2, 0, 0, 0);
    acc3 = __builtin_amdgcn_mfma_f32_16x16x32_bf16(a3, wb, acc3, 0, 0, 0);
  }
  // C/D layout: col(lane&15)=W-row(n), row=(lane>>4)*4+i=A-row(m)  [m89-verified]
  float* ob = Outp + (size_t)ks * 64 * N + n0 + lrow;
#pragma unroll
  for (int i = 0; i < 4; ++i) {
    ob[(size_t)(lk * 4 + i) * N]      = acc0[i];
    ob[(size_t)(16 + lk * 4 + i) * N] = acc1[i];
    ob[(size_t)(32 + lk * 4 + i) * N] = acc2[i];
    ob[(size_t)(48 + lk * 4 + i) * N] = acc3[i];
  }
}

__device__ __forceinline__ float block_reduce_sum256(float v, float* red, int t) {
#pragma unroll
  for (int o = 32; o > 0; o >>= 1) v += __shfl_xor(v, o, 64);
  __syncthreads();
  if ((t & 63) == 0) red[t >> 6] = v;
  __syncthreads();
  return red[0] + red[1] + red[2] + red[3];
}

// one block per (b, head); 256 threads. Reads proj = pp0 + pp1 (split-K partials).
__global__ __launch_bounds__(256) void state_update(
    const float* __restrict__ pp0, const float* __restrict__ pp1,
    const float* __restrict__ h,
    const float* __restrict__ B_prev, const float* __restrict__ x_prev,
    const float* __restrict__ theta_cumsum, const float* __restrict__ A_log,
    const float* __restrict__ B_bias, const float* __restrict__ C_bias,
    float* __restrict__ o_h, float* __restrict__ o_B,
    float* __restrict__ o_xp, float* __restrict__ o_th,
    short* __restrict__ ysbf) {
  const int bid = blockIdx.x;            // b*32 + hd
  const int b = bid >> 5, hd = bid & 31;
  const int t = threadIdx.x;
  const size_t pb = (size_t)b * 18496;
#define PJ(o) (pp0[pb + (o)] + pp1[pb + (o)])

  __shared__ float sB[128], sC[128], sBp[128], sXp[128], sXv[128];
  __shared__ float red[8];
  __shared__ float yred[8][128];

  float aval = (t < 128) ? expf(A_log[hd * 128 + t]) : 0.f;
  float brv  = (t < 128) ? PJ(8192 + hd * 128 + t) : 0.f;
  float crv  = (t < 128) ? PJ(12288 + hd * 128 + t) : 0.f;
  if (t < 128) {
    sBp[t] = B_prev[(size_t)bid * 128 + t];
    float xp = PJ(hd * 128 + t);
    sXp[t] = xp;
    o_xp[(size_t)bid * 128 + t] = xp;
    sXv[t] = x_prev[(size_t)bid * 128 + t];
  }
  float sumA  = block_reduce_sum256(aval, red, t);
  float sumB2 = block_reduce_sum256(brv * brv, red, t);
  float sumC2 = block_reduce_sum256(crv * crv, red, t);

  const float dt_raw  = PJ(16384 + hd);
  const float lam_raw = PJ(16416 + hd);
  const float dt  = (dt_raw > 20.f) ? dt_raw : log1pf(expf(dt_raw));
  const float lam = 1.f / (1.f + expf(-lam_raw));
  const float A     = -sumA * (1.f / 128.f);
  const float alpha = expf(dt * A);
  const float beta  = (1.f - lam) * dt * alpha;
  const float gamma = lam * dt;
  const float rb = rsqrtf(sumB2 * (1.f / 128.f) + EPSV);
  const float rc = rsqrtf(sumC2 * (1.f / 128.f) + EPSV);

  if (t < 64) {
    float b0 = PJ(8192 + hd * 128 + 2 * t);
    float b1 = PJ(8192 + hd * 128 + 2 * t + 1);
    float c0 = PJ(12288 + hd * 128 + 2 * t);
    float c1 = PJ(12288 + hd * 128 + 2 * t + 1);
    b0 = b0 * rb + B_bias[hd * 128 + 2 * t];
    b1 = b1 * rb + B_bias[hd * 128 + 2 * t + 1];
    c0 = c0 * rc + C_bias[hd * 128 + 2 * t];
    c1 = c1 * rc + C_bias[hd * 128 + 2 * t + 1];
    const float th = theta_cumsum[(size_t)bid * 64 + t]
                   + PJ(16448 + hd * 64 + t) * dt;
    o_th[(size_t)bid * 64 + t] = th;
    const float cth = cosf(th), sth = sinf(th);
    const float nb0 = b0 * cth - b1 * sth, nb1 = b0 * sth + b1 * cth;
    const float nc0 = c0 * cth - c1 * sth, nc1 = c0 * sth + c1 * cth;
    sB[2 * t] = nb0; sB[2 * t + 1] = nb1;
    sC[2 * t] = nc0; sC[2 * t + 1] = nc1;
    o_B[(size_t)bid * 128 + 2 * t] = nb0;
    o_B[(size_t)bid * 128 + 2 * t + 1] = nb1;
  }
  __syncthreads();

  // h_new = alpha*h + beta*Bp(x)xv + gamma*B(x)xp ; y[p] += C[n]*h_new[n][p]
  const int p4 = t & 31, nb = t >> 5;
  const float4 xp4 = *(const float4*)&sXp[p4 * 4];
  const float4 xv4 = *(const float4*)&sXv[p4 * 4];
  const size_t hbase = (size_t)bid * 16384;
  float4 ya = {0.f, 0.f, 0.f, 0.f};
  for (int n = nb; n < 128; n += 8) {
    const float4 hv = *(const float4*)&h[hbase + n * 128 + p4 * 4];
    const float cb = gamma * sB[n];
    const float cp = beta * sBp[n];
    float4 hn;
    hn.x = alpha * hv.x + cp * xv4.x + cb * xp4.x;
    hn.y = alpha * hv.y + cp * xv4.y + cb * xp4.y;
    hn.z = alpha * hv.z + cp * xv4.z + cb * xp4.z;
    hn.w = alpha * hv.w + cp * xv4.w + cb * xp4.w;
    *(float4*)&o_h[hbase + n * 128 + p4 * 4] = hn;
    const float cn = sC[n];
    ya.x += cn * hn.x; ya.y += cn * hn.y; ya.z += cn * hn.z; ya.w += cn * hn.w;
  }
  *(float4*)&yred[nb][p4 * 4] = ya;
  __syncthreads();
  if (t < 128) {
    float y = 0.f;
#pragma unroll
    for (int j = 0; j < 8; ++j) y += yred[j][t];
    const float zv = PJ(4096 + hd * 128 + t);
    const float sig = 1.f / (1.f + expf(-zv));
    ysbf[(size_t)b * 4096 + hd * 128 + t] = f2b(y * zv * sig);
  }
#undef PJ
}

// y[64][2048] = sum over 8 K-split partials
__global__ __launch_bounds__(256) void reduce_y(
    const float* __restrict__ yp, float* __restrict__ y, int n4) {
  const int i = blockIdx.x * 256 + threadIdx.x;
  if (i < n4) {
    float4 s = ((const float4*)yp)[i];
#pragma unroll
    for (int k = 1; k < 8; ++k) {
      float4 t = ((const float4*)(yp + (size_t)k * 131072))[i];
      s.x += t.x; s.y += t.y; s.z += t.z; s.w += t.w;
    }
    ((float4*)y)[i] = s;
  }
}

extern "C" void kernel_launch(void* const* d_in, const int* in_sizes, int n_in,
                              void* d_out, int out_size, void* d_ws, size_t ws_size,
                              hipStream_t stream) {
  const float* x            = (const float*)d_in[0];
  const float* h            = (const float*)d_in[1];
  const float* B_prev       = (const float*)d_in[2];
  const float* x_prev       = (const float*)d_in[3];
  const float* theta_cumsum = (const float*)d_in[4];
  const float* W_in         = (const float*)d_in[5];
  const float* A_log        = (const float*)d_in[6];
  const float* B_bias       = (const float*)d_in[7];
  const float* C_bias       = (const float*)d_in[8];
  const float* W_out        = (const float*)d_in[9];

  float* out  = (float*)d_out;
  float* o_y  = out;                        // 64*2048
  float* o_h  = out + 131072;               // 64*32*128*128
  float* o_B  = o_h + 33554432;             // 64*32*128
  float* o_xp = o_B + 262144;               // 64*32*128
  float* o_th = o_xp + 262144;              // 64*32*64

  // ws layout
  float* pp   = (float*)d_ws;               // 2 x 64*18496 fp32 split-K partials
  float* yp   = pp;                         // 8 x 64*2048 fp32 (reuses pp after state_update)
  short* xbf  = (short*)(pp + 2 * 1183744); // 64*2048 bf16
  short* ysbf = xbf + 131072;               // 64*4096 bf16

  // 1) x -> bf16
  conv_bf16<<<dim3(64), dim3(256), 0, stream>>>(x, xbf, 16384);
  // 2) proj partials = xbf @ W_in^T   (N=18496, K=2048, split-K=2)
  gemm_stream<1, 32><<<dim3(578), dim3(256), 0, stream>>>(xbf, W_in, pp, 18496, 2048);
  // 3) fused state update (sums the 2 partials at load)
  state_update<<<dim3(2048), dim3(256), 0, stream>>>(
      pp, pp + 1183744, h, B_prev, x_prev, theta_cumsum, A_log, B_bias, C_bias,
      o_h, o_B, o_xp, o_th, ysbf);
  // 4) y partials = ysbf @ W_out^T    (N=2048, K=4096, split-K=8)
  gemm_stream<3, 16><<<dim3(256), dim3(256), 0, stream>>>(ysbf, W_out, yp, 2048, 4096);
  // 5) final y reduce
  reduce_y<<<dim3(128), dim3(256), 0, stream>>>(yp, o_y, 32768);
}

// Round 3
// 133.075 us; speedup vs baseline: 1.6160x; 1.2388x over previous
//
#include <hip/hip_runtime.h>
#include <hip/hip_bf16.h>
#include <cstdint>
#include <cmath>

#define EPSV 1e-6f

typedef __attribute__((ext_vector_type(8))) short bf16x8;
typedef __attribute__((ext_vector_type(4))) float f32x4;

typedef __attribute__((address_space(3))) unsigned int lds_u32;
typedef const __attribute__((address_space(1))) unsigned int g_u32;

__device__ __forceinline__ void load_lds16(const void* g, void* l) {
  // 16B per lane, dest = wave-uniform base + lane*16 (linear)
  __builtin_amdgcn_global_load_lds((g_u32*)g, (lds_u32*)l, 16, 0, 0);
}

__device__ __forceinline__ short f2b(float f) {
  unsigned u = __float_as_uint(f);
  u = (u + 0x7fffu + ((u >> 16) & 1u)) >> 16;   // RNE fp32 -> bf16
  return (short)u;
}

__device__ __forceinline__ bf16x8 cvt8(float4 a, float4 b) {
  bf16x8 v;
  v[0]=f2b(a.x); v[1]=f2b(a.y); v[2]=f2b(a.z); v[3]=f2b(a.w);
  v[4]=f2b(b.x); v[5]=f2b(b.y); v[6]=f2b(b.z); v[7]=f2b(b.w);
  return v;
}

// fp32 -> bf16 bulk convert (for the small A matrix)
__global__ __launch_bounds__(256) void conv_bf16(
    const float* __restrict__ in, short* __restrict__ out, int n8) {
  const int i = blockIdx.x * 256 + threadIdx.x;
  if (i < n8) {
    float4 a = ((const float4*)in)[2 * i];
    float4 b = ((const float4*)in)[2 * i + 1];
    ((bf16x8*)out)[i] = cvt8(a, b);
  }
}

// Outp[ks][64][N] = Abf[64, K-slice] @ W[N, K-slice]^T   (bf16 MFMA)
// 2-phase global_load_lds template: tile 64x32xBK64, dbuf LDS, 256 thr.
// W staged as fp32 (converted on LDS read), A staged as bf16.
// LDS layouts are linear-in-lane-order (gload_lds requirement); bank
// swizzle done by permuting the per-lane GLOBAL source granule.
template<int KSPLIT>
__global__ __launch_bounds__(256) void gemm_lds(
    const short* __restrict__ Abf, const float* __restrict__ W,
    float* __restrict__ Outp, int N, int K) {
  __shared__ float Wlds[2][32 * 64];   // row*64 floats; granule=16B, slot g^(r&15)
  __shared__ short Xlds[2][64 * 64];   // row*64 bf16;   granule=16B, slot g^(r&7)
  const int tid = threadIdx.x;
  const int lane = tid & 63;
  const int wv = tid >> 6;
  const int lrow = lane & 15, lk = lane >> 4;
  const int bid = blockIdx.x;
  const int ks = bid % KSPLIT;
  const int n0 = (bid / KSPLIT) * 32;
  const int Klen = K / KSPLIT;
  const int nt = Klen / 64;
  const int kbase = ks * Klen;

  f32x4 acc[2];
  acc[0] = (f32x4){0.f,0.f,0.f,0.f};
  acc[1] = (f32x4){0.f,0.f,0.f,0.f};

  auto stage = [&](int buf, int k0) {
#pragma unroll
    for (int j = 0; j < 2; ++j) {
      const int c = 2 * wv + j;                 // chunk 0..7 (1KB each)
      // W chunk: rows 4c..4c+3, 16 granule-slots per row
      const int rw = c * 4 + (lane >> 4);
      const int gw = (lane & 15) ^ (rw & 15);
      load_lds16(W + (size_t)(n0 + rw) * K + k0 + gw * 4,
                 (char*)&Wlds[buf][0] + c * 1024);
      // A chunk: rows 8c..8c+7, 8 granule-slots per row
      const int rx = c * 8 + (lane >> 3);
      const int gx = (lane & 7) ^ (rx & 7);
      load_lds16(Abf + (size_t)rx * K + k0 + gx * 8,
                 (char*)&Xlds[buf][0] + c * 1024);
    }
  };

  auto compute = [&](int buf) {
#pragma unroll
    for (int kc = 0; kc < 2; ++kc) {
      const int rn = (wv & 1) * 16 + lrow;
      const int g0 = kc * 8 + 2 * lk;
      const float4 wlo = *(const float4*)((const char*)&Wlds[buf][0]
                          + rn * 256 + ((g0 ^ (rn & 15)) * 16));
      const float4 whi = *(const float4*)((const char*)&Wlds[buf][0]
                          + rn * 256 + (((g0 + 1) ^ (rn & 15)) * 16));
      const bf16x8 wb = cvt8(wlo, whi);
#pragma unroll
      for (int mf = 0; mf < 2; ++mf) {
        const int rm = (wv >> 1) * 32 + mf * 16 + lrow;
        const int gx = kc * 4 + lk;
        const bf16x8 av = *(const bf16x8*)((const char*)&Xlds[buf][0]
                           + rm * 128 + ((gx ^ (rm & 7)) * 16));
        acc[mf] = __builtin_amdgcn_mfma_f32_16x16x32_bf16(av, wb, acc[mf], 0, 0, 0);
      }
    }
  };

  stage(0, kbase);
  __syncthreads();
  int cur = 0;
  for (int t = 0; t < nt - 1; ++t) {
    stage(cur ^ 1, kbase + (t + 1) * 64);   // issue next tile (no VGPR dest)
    compute(cur);                           // MFMA current tile
    __syncthreads();                        // drains vmcnt(0), flips buffers
    cur ^= 1;
  }
  compute(cur);

  // C/D layout: col(lane&15)=n, row=(lane>>4)*4+i=m  [m89-verified]
  float* ob = Outp + (size_t)ks * 64 * N + n0 + (wv & 1) * 16 + lrow;
#pragma unroll
  for (int mf = 0; mf < 2; ++mf)
#pragma unroll
    for (int i = 0; i < 4; ++i)
      ob[(size_t)((wv >> 1) * 32 + mf * 16 + lk * 4 + i) * N] = acc[mf][i];
}

__device__ __forceinline__ float block_reduce_sum256(float v, float* red, int t) {
#pragma unroll
  for (int o = 32; o > 0; o >>= 1) v += __shfl_xor(v, o, 64);
  __syncthreads();
  if ((t & 63) == 0) red[t >> 6] = v;
  __syncthreads();
  return red[0] + red[1] + red[2] + red[3];
}

// one block per (b, head); 256 threads. proj = pp0 + pp1 (split-K partials).
__global__ __launch_bounds__(256) void state_update(
    const float* __restrict__ pp0, const float* __restrict__ pp1,
    const float* __restrict__ h,
    const float* __restrict__ B_prev, const float* __restrict__ x_prev,
    const float* __restrict__ theta_cumsum, const float* __restrict__ A_log,
    const float* __restrict__ B_bias, const float* __restrict__ C_bias,
    float* __restrict__ o_h, float* __restrict__ o_B,
    float* __restrict__ o_xp, float* __restrict__ o_th,
    short* __restrict__ ysbf) {
  const int bid = blockIdx.x;            // b*32 + hd
  const int b = bid >> 5, hd = bid & 31;
  const int t = threadIdx.x;
  const size_t pb = (size_t)b * 18496;
#define PJ(o) (pp0[pb + (o)] + pp1[pb + (o)])

  __shared__ float sB[128], sC[128], sBp[128], sXp[128], sXv[128];
  __shared__ float red[8];
  __shared__ float yred[8][128];

  float aval = (t < 128) ? expf(A_log[hd * 128 + t]) : 0.f;
  float brv  = (t < 128) ? PJ(8192 + hd * 128 + t) : 0.f;
  float crv  = (t < 128) ? PJ(12288 + hd * 128 + t) : 0.f;
  if (t < 128) {
    sBp[t] = B_prev[(size_t)bid * 128 + t];
    float xp = PJ(hd * 128 + t);
    sXp[t] = xp;
    o_xp[(size_t)bid * 128 + t] = xp;
    sXv[t] = x_prev[(size_t)bid * 128 + t];
  }
  float sumA  = block_reduce_sum256(aval, red, t);
  float sumB2 = block_reduce_sum256(brv * brv, red, t);
  float sumC2 = block_reduce_sum256(crv * crv, red, t);

  const float dt_raw  = PJ(16384 + hd);
  const float lam_raw = PJ(16416 + hd);
  const float dt  = (dt_raw > 20.f) ? dt_raw : log1pf(expf(dt_raw));
  const float lam = 1.f / (1.f + expf(-lam_raw));
  const float A     = -sumA * (1.f / 128.f);
  const float alpha = expf(dt * A);
  const float beta  = (1.f - lam) * dt * alpha;
  const float gamma = lam * dt;
  const float rb = rsqrtf(sumB2 * (1.f / 128.f) + EPSV);
  const float rc = rsqrtf(sumC2 * (1.f / 128.f) + EPSV);

  if (t < 64) {
    float b0 = PJ(8192 + hd * 128 + 2 * t);
    float b1 = PJ(8192 + hd * 128 + 2 * t + 1);
    float c0 = PJ(12288 + hd * 128 + 2 * t);
    float c1 = PJ(12288 + hd * 128 + 2 * t + 1);
    b0 = b0 * rb + B_bias[hd * 128 + 2 * t];
    b1 = b1 * rb + B_bias[hd * 128 + 2 * t + 1];
    c0 = c0 * rc + C_bias[hd * 128 + 2 * t];
    c1 = c1 * rc + C_bias[hd * 128 + 2 * t + 1];
    const float th = theta_cumsum[(size_t)bid * 64 + t]
                   + PJ(16448 + hd * 64 + t) * dt;
    o_th[(size_t)bid * 64 + t] = th;
    const float cth = cosf(th), sth = sinf(th);
    const float nb0 = b0 * cth - b1 * sth, nb1 = b0 * sth + b1 * cth;
    const float nc0 = c0 * cth - c1 * sth, nc1 = c0 * sth + c1 * cth;
    sB[2 * t] = nb0; sB[2 * t + 1] = nb1;
    sC[2 * t] = nc0; sC[2 * t + 1] = nc1;
    o_B[(size_t)bid * 128 + 2 * t] = nb0;
    o_B[(size_t)bid * 128 + 2 * t + 1] = nb1;
  }
  __syncthreads();

  // h_new = alpha*h + beta*Bp(x)xv + gamma*B(x)xp ; y[p] += C[n]*h_new[n][p]
  const int p4 = t & 31, nb = t >> 5;
  const float4 xp4 = *(const float4*)&sXp[p4 * 4];
  const float4 xv4 = *(const float4*)&sXv[p4 * 4];
  const size_t hbase = (size_t)bid * 16384;
  float4 ya = {0.f, 0.f, 0.f, 0.f};
  for (int n = nb; n < 128; n += 8) {
    const float4 hv = *(const float4*)&h[hbase + n * 128 + p4 * 4];
    const float cb = gamma * sB[n];
    const float cp = beta * sBp[n];
    float4 hn;
    hn.x = alpha * hv.x + cp * xv4.x + cb * xp4.x;
    hn.y = alpha * hv.y + cp * xv4.y + cb * xp4.y;
    hn.z = alpha * hv.z + cp * xv4.z + cb * xp4.z;
    hn.w = alpha * hv.w + cp * xv4.w + cb * xp4.w;
    *(float4*)&o_h[hbase + n * 128 + p4 * 4] = hn;
    const float cn = sC[n];
    ya.x += cn * hn.x; ya.y += cn * hn.y; ya.z += cn * hn.z; ya.w += cn * hn.w;
  }
  *(float4*)&yred[nb][p4 * 4] = ya;
  __syncthreads();
  if (t < 128) {
    float y = 0.f;
#pragma unroll
    for (int j = 0; j < 8; ++j) y += yred[j][t];
    const float zv = PJ(4096 + hd * 128 + t);
    const float sig = 1.f / (1.f + expf(-zv));
    ysbf[(size_t)b * 4096 + hd * 128 + t] = f2b(y * zv * sig);
  }
#undef PJ
}

// y[64][2048] = sum over 8 K-split partials
__global__ __launch_bounds__(256) void reduce_y(
    const float* __restrict__ yp, float* __restrict__ y, int n4) {
  const int i = blockIdx.x * 256 + threadIdx.x;
  if (i < n4) {
    float4 s = ((const float4*)yp)[i];
#pragma unroll
    for (int k = 1; k < 8; ++k) {
      float4 t = ((const float4*)(yp + (size_t)k * 131072))[i];
      s.x += t.x; s.y += t.y; s.z += t.z; s.w += t.w;
    }
    ((float4*)y)[i] = s;
  }
}

extern "C" void kernel_launch(void* const* d_in, const int* in_sizes, int n_in,
                              void* d_out, int out_size, void* d_ws, size_t ws_size,
                              hipStream_t stream) {
  const float* x            = (const float*)d_in[0];
  const float* h            = (const float*)d_in[1];
  const float* B_prev       = (const float*)d_in[2];
  const float* x_prev       = (const float*)d_in[3];
  const float* theta_cumsum = (const float*)d_in[4];
  const float* W_in         = (const float*)d_in[5];
  const float* A_log        = (const float*)d_in[6];
  const float* B_bias       = (const float*)d_in[7];
  const float* C_bias       = (const float*)d_in[8];
  const float* W_out        = (const float*)d_in[9];

  float* out  = (float*)d_out;
  float* o_y  = out;                        // 64*2048
  float* o_h  = out + 131072;               // 64*32*128*128
  float* o_B  = o_h + 33554432;             // 64*32*128
  float* o_xp = o_B + 262144;               // 64*32*128
  float* o_th = o_xp + 262144;              // 64*32*64

  // ws layout
  float* pp   = (float*)d_ws;               // 2 x 64*18496 fp32 split-K partials
  float* yp   = pp;                         // 8 x 64*2048 fp32 (reuse after state_update)
  short* xbf  = (short*)(pp + 2 * 1183744); // 64*2048 bf16
  short* ysbf = xbf + 131072;               // 64*4096 bf16

  // 1) x -> bf16
  conv_bf16<<<dim3(64), dim3(256), 0, stream>>>(x, xbf, 16384);
  // 2) proj partials = xbf @ W_in^T   (N=18496, K=2048, split-K=2)
  gemm_lds<2><<<dim3(578 * 2), dim3(256), 0, stream>>>(xbf, W_in, pp, 18496, 2048);
  // 3) fused state update (sums the 2 partials at load)
  state_update<<<dim3(2048), dim3(256), 0, stream>>>(
      pp, pp + 1183744, h, B_prev, x_prev, theta_cumsum, A_log, B_bias, C_bias,
      o_h, o_B, o_xp, o_th, ysbf);
  // 4) y partials = ysbf @ W_out^T    (N=2048, K=4096, split-K=8)
  gemm_lds<8><<<dim3(64 * 8), dim3(256), 0, stream>>>(ysbf, W_out, yp, 2048, 4096);
  // 5) final y reduce
  reduce_y<<<dim3(128), dim3(256), 0, stream>>>(yp, o_y, 32768);
}

// Round 4
// 126.356 us; speedup vs baseline: 1.7019x; 1.0532x over previous
//
#include <hip/hip_runtime.h>
#include <hip/hip_bf16.h>
#include <cstdint>
#include <cmath>

#define EPSV 1e-6f

typedef __attribute__((ext_vector_type(8))) short bf16x8;
typedef __attribute__((ext_vector_type(4))) float f32x4;

typedef __attribute__((address_space(3))) unsigned int lds_u32;
typedef const __attribute__((address_space(1))) unsigned int g_u32;

__device__ __forceinline__ void load_lds16(const void* g, void* l) {
  // 16B per lane, dest = wave-uniform base + lane*16 (linear)
  __builtin_amdgcn_global_load_lds((g_u32*)g, (lds_u32*)l, 16, 0, 0);
}

__device__ __forceinline__ short f2b(float f) {
  unsigned u = __float_as_uint(f);
  u = (u + 0x7fffu + ((u >> 16) & 1u)) >> 16;   // RNE fp32 -> bf16
  return (short)u;
}

__device__ __forceinline__ bf16x8 cvt8(float4 a, float4 b) {
  bf16x8 v;
  v[0]=f2b(a.x); v[1]=f2b(a.y); v[2]=f2b(a.z); v[3]=f2b(a.w);
  v[4]=f2b(b.x); v[5]=f2b(b.y); v[6]=f2b(b.z); v[7]=f2b(b.w);
  return v;
}

// fp32 -> bf16 bulk convert (for the small A matrix)
__global__ __launch_bounds__(256) void conv_bf16(
    const float* __restrict__ in, short* __restrict__ out, int n8) {
  const int i = blockIdx.x * 256 + threadIdx.x;
  if (i < n8) {
    float4 a = ((const float4*)in)[2 * i];
    float4 b = ((const float4*)in)[2 * i + 1];
    ((bf16x8*)out)[i] = cvt8(a, b);
  }
}

// Outp[ks][64][N] = Abf[64, K-slice] @ W[N, K-slice]^T   (bf16 MFMA)
// 3-deep counted-vmcnt pipeline (T3+T4): 3 LDS buffers, steady-state
// s_waitcnt vmcnt(8) -- loads stay in flight across barriers, never
// drained to 0 until the tail. W staged fp32 (cvt on LDS read), A bf16.
// LDS dest linear (gload_lds rule); bank swizzle via per-lane GLOBAL
// source granule permutation (both-sides-or-neither, rule 21).
template<int KSPLIT>
__global__ __launch_bounds__(256) void gemm_lds(
    const short* __restrict__ Abf, const float* __restrict__ W,
    float* __restrict__ Outp, int N, int K) {
  __shared__ float Wlds[3][32 * 64];   // granule=16B, slot g^(r&15)
  __shared__ short Xlds[3][64 * 64];   // granule=16B, slot g^(r&7)
  const int tid = threadIdx.x;
  const int lane = tid & 63;
  const int wv = tid >> 6;
  const int lrow = lane & 15, lk = lane >> 4;
  const int bid = blockIdx.x;
  const int ks = bid % KSPLIT;
  const int n0 = (bid / KSPLIT) * 32;
  const int Klen = K / KSPLIT;
  const int nt = Klen / 64;
  const int kbase = ks * Klen;

  f32x4 acc[2];
  acc[0] = (f32x4){0.f,0.f,0.f,0.f};
  acc[1] = (f32x4){0.f,0.f,0.f,0.f};

  auto stage = [&](int buf, int k0) {
#pragma unroll
    for (int j = 0; j < 2; ++j) {
      const int c = 2 * wv + j;                 // chunk 0..7 (1KB each)
      const int rw = c * 4 + (lane >> 4);
      const int gw = (lane & 15) ^ (rw & 15);
      load_lds16(W + (size_t)(n0 + rw) * K + k0 + gw * 4,
                 (char*)&Wlds[buf][0] + c * 1024);
      const int rx = c * 8 + (lane >> 3);
      const int gx = (lane & 7) ^ (rx & 7);
      load_lds16(Abf + (size_t)rx * K + k0 + gx * 8,
                 (char*)&Xlds[buf][0] + c * 1024);
    }
  };

  auto compute = [&](int buf) {
#pragma unroll
    for (int kc = 0; kc < 2; ++kc) {
      const int rn = (wv & 1) * 16 + lrow;
      const int g0 = kc * 8 + 2 * lk;
      const float4 wlo = *(const float4*)((const char*)&Wlds[buf][0]
                          + rn * 256 + ((g0 ^ (rn & 15)) * 16));
      const float4 whi = *(const float4*)((const char*)&Wlds[buf][0]
                          + rn * 256 + (((g0 + 1) ^ (rn & 15)) * 16));
      const bf16x8 wb = cvt8(wlo, whi);
#pragma unroll
      for (int mf = 0; mf < 2; ++mf) {
        const int rm = (wv >> 1) * 32 + mf * 16 + lrow;
        const int gx = kc * 4 + lk;
        const bf16x8 av = *(const bf16x8*)((const char*)&Xlds[buf][0]
                           + rm * 128 + ((gx ^ (rm & 7)) * 16));
        acc[mf] = __builtin_amdgcn_mfma_f32_16x16x32_bf16(av, wb, acc[mf], 0, 0, 0);
      }
    }
  };

  // prologue: 2 tiles in flight (8 loads/thread outstanding)
  stage(0, kbase);
  if (nt > 1) stage(1, kbase + 64);

  for (int t = 0; t < nt; ++t) {
    // wave's previous-tile ds_reads fully done before buffers recycle
    asm volatile("s_waitcnt lgkmcnt(0)" ::: "memory");
    __builtin_amdgcn_sched_barrier(0);
    __builtin_amdgcn_s_barrier();            // b1: all waves done compute(t-1)
    if (t + 2 < nt) {
      stage((t + 2) % 3, kbase + (t + 2) * 64);   // +4 loads -> 12 in flight
      asm volatile("s_waitcnt vmcnt(8)" ::: "memory");  // tile t retired
    } else if (t + 1 < nt) {
      asm volatile("s_waitcnt vmcnt(4)" ::: "memory");
    } else {
      asm volatile("s_waitcnt vmcnt(0)" ::: "memory");
    }
    __builtin_amdgcn_sched_barrier(0);
    __builtin_amdgcn_s_barrier();            // b2: tile t visible to all waves
    compute(t % 3);
  }

  // C/D layout: col(lane&15)=n, row=(lane>>4)*4+i=m  [m89-verified]
  float* ob = Outp + (size_t)ks * 64 * N + n0 + (wv & 1) * 16 + lrow;
#pragma unroll
  for (int mf = 0; mf < 2; ++mf)
#pragma unroll
    for (int i = 0; i < 4; ++i)
      ob[(size_t)((wv >> 1) * 32 + mf * 16 + lk * 4 + i) * N] = acc[mf][i];
}

__device__ __forceinline__ float block_reduce_sum256(float v, float* red, int t) {
#pragma unroll
  for (int o = 32; o > 0; o >>= 1) v += __shfl_xor(v, o, 64);
  __syncthreads();
  if ((t & 63) == 0) red[t >> 6] = v;
  __syncthreads();
  return red[0] + red[1] + red[2] + red[3];
}

// one block per (b, head); 256 threads. proj = pp0 + pp1 (split-K partials).
__global__ __launch_bounds__(256) void state_update(
    const float* __restrict__ pp0, const float* __restrict__ pp1,
    const float* __restrict__ h,
    const float* __restrict__ B_prev, const float* __restrict__ x_prev,
    const float* __restrict__ theta_cumsum, const float* __restrict__ A_log,
    const float* __restrict__ B_bias, const float* __restrict__ C_bias,
    float* __restrict__ o_h, float* __restrict__ o_B,
    float* __restrict__ o_xp, float* __restrict__ o_th,
    short* __restrict__ ysbf) {
  const int bid = blockIdx.x;            // b*32 + hd
  const int b = bid >> 5, hd = bid & 31;
  const int t = threadIdx.x;
  const size_t pb = (size_t)b * 18496;
#define PJ(o) (pp0[pb + (o)] + pp1[pb + (o)])

  __shared__ float sB[128], sC[128], sBp[128], sXp[128], sXv[128];
  __shared__ float red[8];
  __shared__ float yred[8][128];

  float aval = (t < 128) ? expf(A_log[hd * 128 + t]) : 0.f;
  float brv  = (t < 128) ? PJ(8192 + hd * 128 + t) : 0.f;
  float crv  = (t < 128) ? PJ(12288 + hd * 128 + t) : 0.f;
  if (t < 128) {
    sBp[t] = B_prev[(size_t)bid * 128 + t];
    float xp = PJ(hd * 128 + t);
    sXp[t] = xp;
    o_xp[(size_t)bid * 128 + t] = xp;
    sXv[t] = x_prev[(size_t)bid * 128 + t];
  }
  float sumA  = block_reduce_sum256(aval, red, t);
  float sumB2 = block_reduce_sum256(brv * brv, red, t);
  float sumC2 = block_reduce_sum256(crv * crv, red, t);

  const float dt_raw  = PJ(16384 + hd);
  const float lam_raw = PJ(16416 + hd);
  const float dt  = (dt_raw > 20.f) ? dt_raw : log1pf(expf(dt_raw));
  const float lam = 1.f / (1.f + expf(-lam_raw));
  const float A     = -sumA * (1.f / 128.f);
  const float alpha = expf(dt * A);
  const float beta  = (1.f - lam) * dt * alpha;
  const float gamma = lam * dt;
  const float rb = rsqrtf(sumB2 * (1.f / 128.f) + EPSV);
  const float rc = rsqrtf(sumC2 * (1.f / 128.f) + EPSV);

  if (t < 64) {
    float b0 = PJ(8192 + hd * 128 + 2 * t);
    float b1 = PJ(8192 + hd * 128 + 2 * t + 1);
    float c0 = PJ(12288 + hd * 128 + 2 * t);
    float c1 = PJ(12288 + hd * 128 + 2 * t + 1);
    b0 = b0 * rb + B_bias[hd * 128 + 2 * t];
    b1 = b1 * rb + B_bias[hd * 128 + 2 * t + 1];
    c0 = c0 * rc + C_bias[hd * 128 + 2 * t];
    c1 = c1 * rc + C_bias[hd * 128 + 2 * t + 1];
    const float th = theta_cumsum[(size_t)bid * 64 + t]
                   + PJ(16448 + hd * 64 + t) * dt;
    o_th[(size_t)bid * 64 + t] = th;
    const float cth = cosf(th), sth = sinf(th);
    const float nb0 = b0 * cth - b1 * sth, nb1 = b0 * sth + b1 * cth;
    const float nc0 = c0 * cth - c1 * sth, nc1 = c0 * sth + c1 * cth;
    sB[2 * t] = nb0; sB[2 * t + 1] = nb1;
    sC[2 * t] = nc0; sC[2 * t + 1] = nc1;
    o_B[(size_t)bid * 128 + 2 * t] = nb0;
    o_B[(size_t)bid * 128 + 2 * t + 1] = nb1;
  }
  __syncthreads();

  // h_new = alpha*h + beta*Bp(x)xv + gamma*B(x)xp ; y[p] += C[n]*h_new[n][p]
  const int p4 = t & 31, nb = t >> 5;
  const float4 xp4 = *(const float4*)&sXp[p4 * 4];
  const float4 xv4 = *(const float4*)&sXv[p4 * 4];
  const size_t hbase = (size_t)bid * 16384;
  float4 ya = {0.f, 0.f, 0.f, 0.f};
  for (int n = nb; n < 128; n += 8) {
    const float4 hv = *(const float4*)&h[hbase + n * 128 + p4 * 4];
    const float cb = gamma * sB[n];
    const float cp = beta * sBp[n];
    float4 hn;
    hn.x = alpha * hv.x + cp * xv4.x + cb * xp4.x;
    hn.y = alpha * hv.y + cp * xv4.y + cb * xp4.y;
    hn.z = alpha * hv.z + cp * xv4.z + cb * xp4.z;
    hn.w = alpha * hv.w + cp * xv4.w + cb * xp4.w;
    *(float4*)&o_h[hbase + n * 128 + p4 * 4] = hn;
    const float cn = sC[n];
    ya.x += cn * hn.x; ya.y += cn * hn.y; ya.z += cn * hn.z; ya.w += cn * hn.w;
  }
  *(float4*)&yred[nb][p4 * 4] = ya;
  __syncthreads();
  if (t < 128) {
    float y = 0.f;
#pragma unroll
    for (int j = 0; j < 8; ++j) y += yred[j][t];
    const float zv = PJ(4096 + hd * 128 + t);
    const float sig = 1.f / (1.f + expf(-zv));
    ysbf[(size_t)b * 4096 + hd * 128 + t] = f2b(y * zv * sig);
  }
#undef PJ
}

// y[64][2048] = sum over 8 K-split partials
__global__ __launch_bounds__(256) void reduce_y(
    const float* __restrict__ yp, float* __restrict__ y, int n4) {
  const int i = blockIdx.x * 256 + threadIdx.x;
  if (i < n4) {
    float4 s = ((const float4*)yp)[i];
#pragma unroll
    for (int k = 1; k < 8; ++k) {
      float4 t = ((const float4*)(yp + (size_t)k * 131072))[i];
      s.x += t.x; s.y += t.y; s.z += t.z; s.w += t.w;
    }
    ((float4*)y)[i] = s;
  }
}

extern "C" void kernel_launch(void* const* d_in, const int* in_sizes, int n_in,
                              void* d_out, int out_size, void* d_ws, size_t ws_size,
                              hipStream_t stream) {
  const float* x            = (const float*)d_in[0];
  const float* h            = (const float*)d_in[1];
  const float* B_prev       = (const float*)d_in[2];
  const float* x_prev       = (const float*)d_in[3];
  const float* theta_cumsum = (const float*)d_in[4];
  const float* W_in         = (const float*)d_in[5];
  const float* A_log        = (const float*)d_in[6];
  const float* B_bias       = (const float*)d_in[7];
  const float* C_bias       = (const float*)d_in[8];
  const float* W_out        = (const float*)d_in[9];

  float* out  = (float*)d_out;
  float* o_y  = out;                        // 64*2048
  float* o_h  = out + 131072;               // 64*32*128*128
  float* o_B  = o_h + 33554432;             // 64*32*128
  float* o_xp = o_B + 262144;               // 64*32*128
  float* o_th = o_xp + 262144;              // 64*32*64

  // ws layout
  float* pp   = (float*)d_ws;               // 2 x 64*18496 fp32 split-K partials
  float* yp   = pp;                         // 8 x 64*2048 fp32 (reuse after state_update)
  short* xbf  = (short*)(pp + 2 * 1183744); // 64*2048 bf16
  short* ysbf = xbf + 131072;               // 64*4096 bf16

  // 1) x -> bf16
  conv_bf16<<<dim3(64), dim3(256), 0, stream>>>(x, xbf, 16384);
  // 2) proj partials = xbf @ W_in^T   (N=18496, K=2048, split-K=2)
  gemm_lds<2><<<dim3(578 * 2), dim3(256), 0, stream>>>(xbf, W_in, pp, 18496, 2048);
  // 3) fused state update (sums the 2 partials at load)
  state_update<<<dim3(2048), dim3(256), 0, stream>>>(
      pp, pp + 1183744, h, B_prev, x_prev, theta_cumsum, A_log, B_bias, C_bias,
      o_h, o_B, o_xp, o_th, ysbf);
  // 4) y partials = ysbf @ W_out^T    (N=2048, K=4096, split-K=8)
  gemm_lds<8><<<dim3(64 * 8), dim3(256), 0, stream>>>(ysbf, W_out, yp, 2048, 4096);
  // 5) final y reduce
  reduce_y<<<dim3(128), dim3(256), 0, stream>>>(yp, o_y, 32768);
}